// Round 16
// baseline (5966.508 us; speedup 1.0000x reference)
//
#include <hip/hip_runtime.h>
#include <math.h>

#define HID 51
#define TMAIN 1024
#define FUT 64
#define TT (TMAIN + FUT)
#define RING 128  // h2 history ring depth (pow2)
#define RROW 52   // h2 ring row floats per seq (51 + pad; 208B, 16B-aligned)
#define PKR 52    // piK gate-row stride in floats

typedef float v2f __attribute__((ext_vector_type(2)));

__device__ __forceinline__ float fast_sigmoid(float x) {
  return 1.0f / (1.0f + __expf(-x));
}
__device__ __forceinline__ float fast_tanh(float x) {
  return 1.0f - 2.0f / (__expf(2.0f * x) + 1.0f);
}

__device__ __forceinline__ float cell_update(const float (&acc)[4],
                                             float& cst) {
  float gi = fast_sigmoid(acc[0]);
  float gf = fast_sigmoid(acc[1]);
  float gg = fast_tanh(acc[2]);
  float go = fast_sigmoid(acc[3]);
  cst = gf * cst + gi * gg;
  return go * fast_tanh(cst);
}

// Dual-sequence cell dot: gate i from REGISTERS (26 v2f, k=0..51 with k51
// weight 0), gates {f,g,o} STREAMED from LDS layout [3][13][52][4] (lane u
// reads float4 at (s*13+q)*208 + u*4 floats: 16B/lane stride -> conflict-
// free full-BW ds_read_b128; addresses static -> pure BW, no h dependency).
// h rows are uniform-address (broadcast) float4 reads; h[51] == 0 always.
__device__ __forceinline__ void cellDot2s(const float* hA, const float* hB,
                                          const float* wsu,  // &ws[0][0][u][0]
                                          const v2f (&wi)[26],
                                          float (&aA)[4], float (&aB)[4]) {
  const float4* a4 = reinterpret_cast<const float4*>(hA);
  const float4* b4 = reinterpret_cast<const float4*>(hB);
  v2f sAi = {0.f, 0.f}, sAf = {0.f, 0.f}, sAg = {0.f, 0.f}, sAo = {0.f, 0.f};
  v2f sBi = {0.f, 0.f}, sBf = {0.f, 0.f}, sBg = {0.f, 0.f}, sBo = {0.f, 0.f};
#pragma unroll
  for (int q = 0; q < 13; ++q) {
    float4 ha = a4[q], hb = b4[q];
    float4 wf = *reinterpret_cast<const float4*>(wsu + (0 * 13 + q) * 208);
    float4 wg = *reinterpret_cast<const float4*>(wsu + (1 * 13 + q) * 208);
    float4 wo = *reinterpret_cast<const float4*>(wsu + (2 * 13 + q) * 208);
    v2f alo = {ha.x, ha.y}, ahi = {ha.z, ha.w};
    v2f blo = {hb.x, hb.y}, bhi = {hb.z, hb.w};
    v2f wflo = {wf.x, wf.y}, wfhi = {wf.z, wf.w};
    v2f wglo = {wg.x, wg.y}, wghi = {wg.z, wg.w};
    v2f wolo = {wo.x, wo.y}, wohi = {wo.z, wo.w};
    sAi = __builtin_elementwise_fma(alo, wi[2 * q + 0], sAi);
    sAi = __builtin_elementwise_fma(ahi, wi[2 * q + 1], sAi);
    sBi = __builtin_elementwise_fma(blo, wi[2 * q + 0], sBi);
    sBi = __builtin_elementwise_fma(bhi, wi[2 * q + 1], sBi);
    sAf = __builtin_elementwise_fma(alo, wflo, sAf);
    sAf = __builtin_elementwise_fma(ahi, wfhi, sAf);
    sBf = __builtin_elementwise_fma(blo, wflo, sBf);
    sBf = __builtin_elementwise_fma(bhi, wfhi, sBf);
    sAg = __builtin_elementwise_fma(alo, wglo, sAg);
    sAg = __builtin_elementwise_fma(ahi, wghi, sAg);
    sBg = __builtin_elementwise_fma(blo, wglo, sBg);
    sBg = __builtin_elementwise_fma(bhi, wghi, sBg);
    sAo = __builtin_elementwise_fma(alo, wolo, sAo);
    sAo = __builtin_elementwise_fma(ahi, wohi, sAo);
    sBo = __builtin_elementwise_fma(blo, wolo, sBo);
    sBo = __builtin_elementwise_fma(bhi, wohi, sBo);
  }
  aA[0] += sAi.x + sAi.y;
  aA[1] += sAf.x + sAf.y;
  aA[2] += sAg.x + sAg.y;
  aA[3] += sAo.x + sAo.y;
  aB[0] += sBi.x + sBi.y;
  aB[1] += sBf.x + sBf.y;
  aB[2] += sBg.x + sBg.y;
  aB[3] += sBo.x + sBo.y;
}

// Quarter dot: 4 gates x 26 K (13 float2 pairs) from a pre-offset pointer.
// K2 waves' pair 12 = {h[50], h[51]=0} x {W[50], 0}.
__device__ __forceinline__ void dotQ(const float* h, const v2f (&w)[4][13],
                                     float (&acc)[4]) {
  const float2* h2p = reinterpret_cast<const float2*>(h);
  v2f s[4] = {{0.f, 0.f}, {0.f, 0.f}, {0.f, 0.f}, {0.f, 0.f}};
#pragma unroll
  for (int p = 0; p < 13; ++p) {
    float2 hv = h2p[p];
    v2f a = {hv.x, hv.y};
#pragma unroll
    for (int g = 0; g < 4; ++g)
      s[g] = __builtin_elementwise_fma(a, w[g][p], s[g]);
  }
#pragma unroll
  for (int g = 0; g < 4; ++g) acc[g] = s[g].x + s[g].y;
}

// One block = TWO sequences, 6 waves. WAVE-LOCAL cells (zero cross-wave
// edges in the serial recurrence) + 4-step barrier intervals (R15 scheme,
// correctness-verified). R15 lesson (4th data point): arch-VGPR demand
// beyond ~128 ALWAYS spills to scratch -> weights that don't fit stream
// from LDS instead, with DUAL-SEQ cell waves so each streamed read serves
// two dots:
//   wid0: L1 cell, BOTH seqs (gate i in 52 regs; f,g,o streamed)
//   wid1: L2 cell, BOTH seqs (same split; carries wlin for feedback head)
//   wid2,3: Wi2 seq0 K[0,26)/K[26,51) (104 regs, proven safe)
//   wid4,5: Wi2 seq1 (same); wid2/wid4 also run the deferred lin-head flush
// Interval iv: L1 k in [4iv,4iv+4) | Wi2 j in [4(iv-1),4iv) |
//              L2 m in [4(iv-2),4(iv-1)) | flush every 16 intervals.
// Ring disjointness (verified in R15): h1 8-deep alternating halves,
// piK 8-deep same, h2 128-deep (flush reads 64 slots >= 5 slots behind
// the writer). Barriers: 1027 -> 259. Feedback = barriered 3 sub-phases.
__global__ __launch_bounds__(384, 2)
void lstm2_persistent(const float* __restrict__ input,
                      const float* __restrict__ Wi1,
                      const float* __restrict__ Wh1,
                      const float* __restrict__ bi1,
                      const float* __restrict__ bh1,
                      const float* __restrict__ Wi2,
                      const float* __restrict__ Wh2,
                      const float* __restrict__ bi2,
                      const float* __restrict__ bh2,
                      const float* __restrict__ Wlin,
                      const float* __restrict__ blin,
                      float* __restrict__ out) {
  __shared__ __align__(16) float lds_x[2][TMAIN];          // 8 KB
  __shared__ __align__(16) float lds_h1[8][2][64];         // 4 KB
  __shared__ __align__(16) float lds_piK1[2][8][4][PKR];   // 13 KB
  __shared__ __align__(16) float lds_piK2[2][8][4][PKR];   // 13 KB
  __shared__ __align__(16) float lds_h2h[RING][2][RROW];   // 52 KB
  __shared__ __align__(16) float lds_ws1[3][13][52][4];    // 31.7 KB (f,g,o L1)
  __shared__ __align__(16) float lds_ws2[3][13][52][4];    // 31.7 KB (f,g,o L2)
  __shared__ __align__(16) float lds_wlin[64];
  __shared__ __align__(16) float lds_outbuf[2][64];
  __shared__ float lds_lin[2];  // out(t) feedback
  __shared__ float lds_fb[2];   // out(1023) seed

  const int tid = threadIdx.x;
  const int s0 = blockIdx.x * 2;  // sequence pair
  const int wid = tid >> 6;       // 0..5
  const int lane = tid & 63;
  const bool act = lane < HID;
  const int u = act ? lane : (HID - 1);  // lane = unit (clamped)

  // ---- staging ----
  for (int i = tid; i < TMAIN; i += 384) {
    lds_x[0][i] = input[s0 * TMAIN + i];
    lds_x[1][i] = input[(s0 + 1) * TMAIN + i];
  }
  for (int i = tid; i < 8 * 2 * 64; i += 384)
    (&lds_h1[0][0][0])[i] = 0.0f;  // lanes 51..63 stay 0 forever
  for (int i = tid; i < RING * 2 * RROW; i += 384)
    (&lds_h2h[0][0][0])[i] = 0.0f;  // element 51 stays 0 forever
  if (tid < 64) lds_wlin[tid] = (tid < HID) ? Wlin[tid] : 0.0f;
  // stream arrays: [s][q][uu][j] = W[(gmap[s]*HID+uu)*HID + 4q+j] or 0
  for (int i = tid; i < 3 * 13 * 52 * 4; i += 384) {
    const int s = i / 2704;         // 13*52*4
    const int r = i - s * 2704;
    const int q = r / 208;          // 52*4
    const int r2 = r - q * 208;
    const int uu = r2 >> 2, j = r2 & 3;
    const int k = 4 * q + j;
    const int gate = s + 1;  // f, g, o
    const bool ok = (uu < HID) && (k < HID);
    (&lds_ws1[0][0][0][0])[i] = ok ? Wh1[(gate * HID + uu) * HID + k] : 0.0f;
    (&lds_ws2[0][0][0][0])[i] = ok ? Wh2[(gate * HID + uu) * HID + k] : 0.0f;
  }

  // ---- per-wave register weights ----
  v2f wi[26];      // cell waves: gate-i row, k pairs (pair 25 = {k50, 0})
  v2f w2q[4][13];  // Wi2 waves: quarter rows
  float bias[4] = {0.f, 0.f, 0.f, 0.f};
  float wi1g[4] = {0.f, 0.f, 0.f, 0.f};
  float wlin_u = 0.0f;
  float cstA = 0.0f, cstB = 0.0f;  // per-seq cell states (cell waves)

  if (wid < 2) {
    const float* Wsel = (wid == 0) ? Wh1 : Wh2;
    const float* row = Wsel + (0 * HID + u) * HID;  // gate i
#pragma unroll
    for (int p = 0; p < 25; ++p) {
      v2f t;
      t.x = row[2 * p + 0];
      t.y = row[2 * p + 1];
      wi[p] = t;
    }
    {
      v2f t;
      t.x = row[50];
      t.y = 0.0f;
      wi[25] = t;
    }
    if (wid == 0) {
#pragma unroll
      for (int g = 0; g < 4; ++g) {
        bias[g] = bi1[g * HID + u] + bh1[g * HID + u];
        wi1g[g] = Wi1[g * HID + u];
      }
    } else {
#pragma unroll
      for (int g = 0; g < 4; ++g)
        bias[g] = bi2[g * HID + u] + bh2[g * HID + u];
      wlin_u = Wlin[u];
    }
#pragma unroll
    for (int p = 0; p < 26; ++p) asm volatile("" : "+v"(wi[p]));
#pragma unroll
    for (int g = 0; g < 4; ++g)
      asm volatile("" : "+v"(bias[g]), "+v"(wi1g[g]));
    asm volatile("" : "+v"(wlin_u));
  } else {
    const int kh = (wid - 2) & 1;  // 0 -> K[0,26), 1 -> K[26,51)
    const int koff = kh * 26;
#pragma unroll
    for (int g = 0; g < 4; ++g) {
      const float* row = Wi2 + (g * HID + u) * HID + koff;
      if (kh == 0) {
#pragma unroll
        for (int p = 0; p < 13; ++p) {
          v2f t;
          t.x = row[2 * p + 0];
          t.y = row[2 * p + 1];
          w2q[g][p] = t;
        }
      } else {
#pragma unroll
        for (int p = 0; p < 12; ++p) {
          v2f t;
          t.x = row[2 * p + 0];
          t.y = row[2 * p + 1];
          w2q[g][p] = t;
        }
        v2f t;
        t.x = row[24];  // K=50
        t.y = 0.0f;     // pairs with h1[51] == 0
        w2q[g][12] = t;
      }
    }
#pragma unroll
    for (int g = 0; g < 4; ++g)
#pragma unroll
      for (int p = 0; p < 13; ++p) asm volatile("" : "+v"(w2q[g][p]));
  }
  const float blin_s = blin[0];

  __syncthreads();

  // ======== main phase: 259 intervals x 4 steps, 1 barrier each ========
  for (int iv = 0; iv <= 258; ++iv) {
    if (wid == 0) {
      // L1 cell, both seqs: 4 sequential steps, fully intra-wave.
      if (iv < 256) {
        const float* wsu = &lds_ws1[0][0][u][0];
        for (int s = 0; s < 4; ++s) {
          const int k = 4 * iv + s;
          float xA = lds_x[0][k], xB = lds_x[1][k];
          float aA[4], aB[4];
#pragma unroll
          for (int g = 0; g < 4; ++g) {
            aA[g] = fmaf(xA, wi1g[g], bias[g]);
            aB[g] = fmaf(xB, wi1g[g], bias[g]);
          }
          cellDot2s(&lds_h1[(k - 1) & 7][0][0], &lds_h1[(k - 1) & 7][1][0],
                    wsu, wi, aA, aB);
          float hA = cell_update(aA, cstA);
          float hB = cell_update(aB, cstB);
          if (act) {
            lds_h1[k & 7][0][u] = hA;
            lds_h1[k & 7][1][u] = hB;
          }
        }
      }
    } else if (wid == 1) {
      // L2 cell, both seqs: consumes piK one interval old.
      if (iv >= 2 && iv <= 257) {
        const float* wsu = &lds_ws2[0][0][u][0];
        for (int s = 0; s < 4; ++s) {
          const int m = 4 * (iv - 2) + s;
          const int pm = m & 7;
          float aA[4], aB[4];
#pragma unroll
          for (int g = 0; g < 4; ++g) {
            aA[g] = bias[g] + lds_piK1[0][pm][g][u] + lds_piK2[0][pm][g][u];
            aB[g] = bias[g] + lds_piK1[1][pm][g][u] + lds_piK2[1][pm][g][u];
          }
          cellDot2s(&lds_h2h[(m - 1) & (RING - 1)][0][0],
                    &lds_h2h[(m - 1) & (RING - 1)][1][0], wsu, wi, aA, aB);
          float hA = cell_update(aA, cstA);
          float hB = cell_update(aB, cstB);
          if (act) {
            lds_h2h[m & (RING - 1)][0][u] = hA;
            lds_h2h[m & (RING - 1)][1][u] = hB;
          }
        }
      }
    } else {
      // Wi2 quarter: consumes h1 one interval old; flush every 16.
      const int seq = (wid - 2) >> 1;
      const int kh = (wid - 2) & 1;
      const int koff = kh * 26;
      if (iv >= 1 && iv <= 256) {
        for (int s = 0; s < 4; ++s) {
          const int j = 4 * (iv - 1) + s;
          float acc[4];
          dotQ(&lds_h1[j & 7][seq][koff], w2q, acc);
          const int pm = j & 7;
          if (act) {
            float* dst =
                kh ? &lds_piK2[seq][pm][0][u] : &lds_piK1[seq][pm][0][u];
            dst[0 * PKR] = acc[0];
            dst[1 * PKR] = acc[1];
            dst[2 * PKR] = acc[2];
            dst[3 * PKR] = acc[3];
          }
        }
      }
      // FLUSH: kh==0 wave of EACH seq (wid2 -> seq0, wid4 -> seq1).
      if (kh == 0 && iv >= 18 && ((iv - 2) & 15) == 0) {
        const int c = 4 * (iv - 2) - 64;
        const int m = c + lane;
        const float* r = &lds_h2h[m & (RING - 1)][seq][0];
        const float4* r4 = reinterpret_cast<const float4*>(r);
        const float4* w4 = reinterpret_cast<const float4*>(lds_wlin);
        float o0 = 0.f, o1 = 0.f, o2 = 0.f, o3 = 0.f;
#pragma unroll
        for (int q = 0; q < 13; ++q) {  // wlin[51] == 0, r[51] == 0
          float4 rv = r4[q];
          float4 wv = w4[q];
          o0 = fmaf(rv.x, wv.x, o0);
          o1 = fmaf(rv.y, wv.y, o1);
          o2 = fmaf(rv.z, wv.z, o2);
          o3 = fmaf(rv.w, wv.w, o3);
        }
        float o = (o0 + o1) + (o2 + o3) + blin_s;
        out[(s0 + seq) * TT + m] = o;
        if (m == TMAIN - 1) lds_fb[seq] = o;  // feedback seed
      }
    }
    __syncthreads();
  }

  // =============== feedback phase: 3 sub-phases, barriered ==============
  for (int t = TMAIN; t < TT; ++t) {
    float phA[4] = {0.f, 0.f, 0.f, 0.f}, phB[4] = {0.f, 0.f, 0.f, 0.f};
    // --- A: L1 cell (both seqs) with feedback x; L2 pre-dots Wh2@h2(t-1) ---
    if (wid == 0) {
      float oA = (t == TMAIN) ? lds_fb[0] : lds_lin[0];
      float oB = (t == TMAIN) ? lds_fb[1] : lds_lin[1];
      float aA[4], aB[4];
#pragma unroll
      for (int g = 0; g < 4; ++g) {
        aA[g] = fmaf(oA, wi1g[g], bias[g]);
        aB[g] = fmaf(oB, wi1g[g], bias[g]);
      }
      cellDot2s(&lds_h1[(t - 1) & 7][0][0], &lds_h1[(t - 1) & 7][1][0],
                &lds_ws1[0][0][u][0], wi, aA, aB);
      float hA = cell_update(aA, cstA);
      float hB = cell_update(aB, cstB);
      if (act) {
        lds_h1[t & 7][0][u] = hA;
        lds_h1[t & 7][1][u] = hB;
      }
    } else if (wid == 1) {
      cellDot2s(&lds_h2h[(t - 1) & (RING - 1)][0][0],
                &lds_h2h[(t - 1) & (RING - 1)][1][0], &lds_ws2[0][0][u][0],
                wi, phA, phB);
    }
    __syncthreads();
    // --- B: Wi2 quarters from h1(t) ---
    if (wid >= 2) {
      const int seq = (wid - 2) >> 1;
      const int kh = (wid - 2) & 1;
      float acc[4];
      dotQ(&lds_h1[t & 7][seq][kh * 26], w2q, acc);
      const int pm = t & 7;
      if (act) {
        float* dst = kh ? &lds_piK2[seq][pm][0][u] : &lds_piK1[seq][pm][0][u];
        dst[0 * PKR] = acc[0];
        dst[1 * PKR] = acc[1];
        dst[2 * PKR] = acc[2];
        dst[3 * PKR] = acc[3];
      }
    }
    __syncthreads();
    // --- C: L2 cell (both seqs) + linear head butterflies ---
    if (wid == 1) {
      const int pm = t & 7;
      float aA[4], aB[4];
#pragma unroll
      for (int g = 0; g < 4; ++g) {
        aA[g] = bias[g] + lds_piK1[0][pm][g][u] + lds_piK2[0][pm][g][u] +
                phA[g];
        aB[g] = bias[g] + lds_piK1[1][pm][g][u] + lds_piK2[1][pm][g][u] +
                phB[g];
      }
      float hA = cell_update(aA, cstA);
      float hB = cell_update(aB, cstB);
      float valA = 0.0f, valB = 0.0f;
      if (act) {
        lds_h2h[t & (RING - 1)][0][u] = hA;
        lds_h2h[t & (RING - 1)][1][u] = hB;
        valA = wlin_u * hA;
        valB = wlin_u * hB;
      }
#pragma unroll
      for (int off = 32; off >= 1; off >>= 1) {
        valA += __shfl_xor(valA, off);
        valB += __shfl_xor(valB, off);
      }
      if (lane == 0) {
        float oA = valA + blin_s;
        float oB = valB + blin_s;
        lds_lin[0] = oA;
        lds_lin[1] = oB;
        lds_outbuf[0][t - TMAIN] = oA;
        lds_outbuf[1][t - TMAIN] = oB;
      }
    }
    __syncthreads();
  }

  // epilogue: flush the 64 future outputs (coalesced)
  if (wid == 2 || wid == 4) {
    const int seq = (wid - 2) >> 1;
    out[(s0 + seq) * TT + TMAIN + lane] = lds_outbuf[seq][lane];
  }
}

extern "C" void kernel_launch(void* const* d_in, const int* in_sizes, int n_in,
                              void* d_out, int out_size, void* d_ws,
                              size_t ws_size, hipStream_t stream) {
  const float* input = (const float*)d_in[0];
  const float* Wi1 = (const float*)d_in[1];
  const float* Wh1 = (const float*)d_in[2];
  const float* bi1 = (const float*)d_in[3];
  const float* bh1 = (const float*)d_in[4];
  const float* Wi2 = (const float*)d_in[5];
  const float* Wh2 = (const float*)d_in[6];
  const float* bi2 = (const float*)d_in[7];
  const float* bh2 = (const float*)d_in[8];
  const float* Wlin = (const float*)d_in[9];
  const float* blin = (const float*)d_in[10];
  float* out = (float*)d_out;

  const int B = in_sizes[0] / TMAIN;  // 512
  lstm2_persistent<<<B / 2, 384, 0, stream>>>(input, Wi1, Wh1, bi1, bh1, Wi2,
                                              Wh2, bi2, bh2, Wlin, blin, out);
}

// Round 17
// 1989.828 us; speedup vs baseline: 2.9985x; 2.9985x over previous
//
#include <hip/hip_runtime.h>
#include <math.h>

#define HID 51
#define TMAIN 1024
#define FUT 64
#define TT (TMAIN + FUT)
#define RING 128  // h2 history ring depth (pow2)
#define RROW 52   // h2 ring row floats per seq (51 + pad, 16B-aligned rows)
#define PKR 52    // piK gate-row stride in floats

typedef float v2f __attribute__((ext_vector_type(2)));

__device__ __forceinline__ float fast_sigmoid(float x) {
  return 1.0f / (1.0f + __expf(-x));
}
__device__ __forceinline__ float fast_tanh(float x) {
  return 1.0f - 2.0f / (__expf(2.0f * x) + 1.0f);
}

__device__ __forceinline__ float cell_update(const float (&acc)[4],
                                             float& cst) {
  float gi = fast_sigmoid(acc[0]);
  float gf = fast_sigmoid(acc[1]);
  float gg = fast_tanh(acc[2]);
  float go = fast_sigmoid(acc[3]);
  cst = gf * cst + gi * gg;
  return go * fast_tanh(cst);
}

// Single-seq cell dot. Gates {i,f} from wreg (wreg[0..25]=i pairs,
// wreg[26..51]=f pairs; pair 25 = {k50, 0}); gates {g,o} streamed from LDS
// layout [2][13][52][4]: lane u reads float4 at (s*13+q)*208 + u*4 floats
// (16B/lane stride -> conflict-free ds_read_b128; static addresses).
// h rows are uniform-address broadcast float4 reads; h[51] == 0 always.
__device__ __forceinline__ void cellDot1s(const float* h, const float* wsu,
                                          const v2f (&wreg)[52],
                                          float (&acc)[4]) {
  const float4* h4 = reinterpret_cast<const float4*>(h);
  v2f sI = {0.f, 0.f}, sF = {0.f, 0.f}, sG = {0.f, 0.f}, sO = {0.f, 0.f};
#pragma unroll
  for (int q = 0; q < 13; ++q) {
    float4 hq = h4[q];
    float4 wg = *reinterpret_cast<const float4*>(wsu + (0 * 13 + q) * 208);
    float4 wo = *reinterpret_cast<const float4*>(wsu + (1 * 13 + q) * 208);
    v2f lo = {hq.x, hq.y}, hi = {hq.z, hq.w};
    sI = __builtin_elementwise_fma(lo, wreg[2 * q + 0], sI);
    sI = __builtin_elementwise_fma(hi, wreg[2 * q + 1], sI);
    sF = __builtin_elementwise_fma(lo, wreg[26 + 2 * q + 0], sF);
    sF = __builtin_elementwise_fma(hi, wreg[26 + 2 * q + 1], sF);
    v2f wglo = {wg.x, wg.y}, wghi = {wg.z, wg.w};
    v2f wolo = {wo.x, wo.y}, wohi = {wo.z, wo.w};
    sG = __builtin_elementwise_fma(lo, wglo, sG);
    sG = __builtin_elementwise_fma(hi, wghi, sG);
    sO = __builtin_elementwise_fma(lo, wolo, sO);
    sO = __builtin_elementwise_fma(hi, wohi, sO);
  }
  acc[0] += sI.x + sI.y;
  acc[1] += sF.x + sF.y;
  acc[2] += sG.x + sG.y;
  acc[3] += sO.x + sO.y;
}

// Quarter dot: 4 gates x 26 K (13 float2 pairs), wreg flat-indexed
// [g*13+p]. K2 waves' pair 12 = {h[50], h[51]=0} x {W[50], 0}.
__device__ __forceinline__ void dotQ(const float* h, const v2f (&wreg)[52],
                                     float (&acc)[4]) {
  const float2* h2p = reinterpret_cast<const float2*>(h);
  v2f s[4] = {{0.f, 0.f}, {0.f, 0.f}, {0.f, 0.f}, {0.f, 0.f}};
#pragma unroll
  for (int p = 0; p < 13; ++p) {
    float2 hv = h2p[p];
    v2f a = {hv.x, hv.y};
#pragma unroll
    for (int g = 0; g < 4; ++g)
      s[g] = __builtin_elementwise_fma(a, wreg[g * 13 + p], s[g]);
  }
#pragma unroll
  for (int g = 0; g < 4; ++g) acc[g] = s[g].x + s[g].y;
}

// One block = TWO sequences, 8 waves, WAVE-LOCAL cells + 4-step barrier
// intervals. R16 lesson (decisive): separate pinned weight arrays per
// role live across the same loop region -> allocator must hold the UNION
// (156-304 floats) -> over the 128-arch wall -> scratch. R5-R9 (clean,
// VGPR 116-124) all used ONE shared array. This round: ONE uniform
// v2f wreg[52] (104 floats, R9's proven budget) for every wave:
//   wid0,1: L1 cell seq0/seq1 (wreg = gates {i,f}; {g,o} streamed)
//   wid2,3: L2 cell seq0/seq1 (same; carries wlin for feedback head)
//   wid4..7: Wi2 quarters seq x K-half (wreg = [4][13])
// Interval iv (1 barrier each, 259 total vs 1027):
//   L1 k in [4iv,4iv+4) | Wi2 j in [4(iv-1),4iv) | L2 m in [4(iv-2),4(iv-1))
//   | lin-head flush (wid4 seq0 / wid6 seq1) every 16 intervals.
// Ring disjointness (verified R15/R16): h1 8-deep opposite halves, piK
// 8-deep same, h2 128-deep (64-slot read window disjoint from 4-slot
// write window mod 128). Serial recurrences 100% intra-wave.
__global__ __launch_bounds__(512, 2)
void lstm2_persistent(const float* __restrict__ input,
                      const float* __restrict__ Wi1,
                      const float* __restrict__ Wh1,
                      const float* __restrict__ bi1,
                      const float* __restrict__ bh1,
                      const float* __restrict__ Wi2,
                      const float* __restrict__ Wh2,
                      const float* __restrict__ bi2,
                      const float* __restrict__ bh2,
                      const float* __restrict__ Wlin,
                      const float* __restrict__ blin,
                      float* __restrict__ out) {
  __shared__ __align__(16) float lds_x[2][TMAIN];         // 8 KB
  __shared__ __align__(16) float lds_h1[8][2][64];        // 4 KB
  __shared__ __align__(16) float lds_piK1[2][8][4][PKR];  // 13.3 KB
  __shared__ __align__(16) float lds_piK2[2][8][4][PKR];  // 13.3 KB
  __shared__ __align__(16) float lds_h2h[RING][2][RROW];  // 53.2 KB
  __shared__ __align__(16) float lds_ws1[2][13][52][4];   // 21.6 KB (g,o L1)
  __shared__ __align__(16) float lds_ws2[2][13][52][4];   // 21.6 KB (g,o L2)
  __shared__ __align__(16) float lds_wlin[64];
  __shared__ __align__(16) float lds_outbuf[2][64];
  __shared__ float lds_lin[2];  // out(t) feedback
  __shared__ float lds_fb[2];   // out(1023) seed

  const int tid = threadIdx.x;
  const int s0 = blockIdx.x * 2;  // sequence pair
  const int wid = tid >> 6;       // 0..7
  const int lane = tid & 63;
  const bool act = lane < HID;
  const int u = act ? lane : (HID - 1);  // lane = unit (clamped)

  // ---- staging ----
  for (int i = tid; i < TMAIN; i += 512) {
    lds_x[0][i] = input[s0 * TMAIN + i];
    lds_x[1][i] = input[(s0 + 1) * TMAIN + i];
  }
  for (int i = tid; i < 8 * 2 * 64; i += 512)
    (&lds_h1[0][0][0])[i] = 0.0f;  // lanes 51..63 stay 0 forever
  for (int i = tid; i < RING * 2 * RROW; i += 512)
    (&lds_h2h[0][0][0])[i] = 0.0f;  // element 51 stays 0 forever
  if (tid < 64) lds_wlin[tid] = (tid < HID) ? Wlin[tid] : 0.0f;
  // stream arrays: [s][q][uu][j] = W[((s+2)*HID+uu)*HID + 4q+j] or 0
  // (s=0 -> gate g, s=1 -> gate o)
  for (int i = tid; i < 2 * 13 * 52 * 4; i += 512) {
    const int s = i / 2704;  // 13*52*4
    const int r = i - s * 2704;
    const int q = r / 208;  // 52*4
    const int r2 = r - q * 208;
    const int uu = r2 >> 2, j = r2 & 3;
    const int k = 4 * q + j;
    const int gate = s + 2;  // g, o
    const bool ok = (uu < HID) && (k < HID);
    (&lds_ws1[0][0][0][0])[i] = ok ? Wh1[(gate * HID + uu) * HID + k] : 0.0f;
    (&lds_ws2[0][0][0][0])[i] = ok ? Wh2[(gate * HID + uu) * HID + k] : 0.0f;
  }

  // ---- uniform per-wave register weights (ONE array for all roles) ----
  v2f wreg[52];  // cells: [0..25]=gate-i pairs, [26..51]=gate-f pairs
                 // Wi2:   [g*13+p] quarter pairs
  float bias[4] = {0.f, 0.f, 0.f, 0.f};
  float wi1g[4] = {0.f, 0.f, 0.f, 0.f};
  float wlin_u = 0.0f;
  float cst = 0.0f;  // cell state (per cell wave)

  if (wid < 4) {
    const int layer = wid >> 1;  // 0 -> L1, 1 -> L2
    const float* Wsel = layer ? Wh2 : Wh1;
#pragma unroll
    for (int gi = 0; gi < 2; ++gi) {  // gates i, f
      const float* row = Wsel + (gi * HID + u) * HID;
#pragma unroll
      for (int p = 0; p < 25; ++p) {
        v2f t;
        t.x = row[2 * p + 0];
        t.y = row[2 * p + 1];
        wreg[26 * gi + p] = t;
      }
      v2f t;
      t.x = row[50];
      t.y = 0.0f;  // pairs with h[51] == 0
      wreg[26 * gi + 25] = t;
    }
    if (layer == 0) {
#pragma unroll
      for (int g = 0; g < 4; ++g) {
        bias[g] = bi1[g * HID + u] + bh1[g * HID + u];
        wi1g[g] = Wi1[g * HID + u];
      }
    } else {
#pragma unroll
      for (int g = 0; g < 4; ++g)
        bias[g] = bi2[g * HID + u] + bh2[g * HID + u];
      wlin_u = Wlin[u];
    }
  } else {
    const int kh = (wid - 4) & 1;  // 0 -> K[0,26), 1 -> K[26,51)
    const int koff = kh * 26;
#pragma unroll
    for (int g = 0; g < 4; ++g) {
      const float* row = Wi2 + (g * HID + u) * HID + koff;
      if (kh == 0) {
#pragma unroll
        for (int p = 0; p < 13; ++p) {
          v2f t;
          t.x = row[2 * p + 0];
          t.y = row[2 * p + 1];
          wreg[g * 13 + p] = t;
        }
      } else {
#pragma unroll
        for (int p = 0; p < 12; ++p) {
          v2f t;
          t.x = row[2 * p + 0];
          t.y = row[2 * p + 1];
          wreg[g * 13 + p] = t;
        }
        v2f t;
        t.x = row[24];  // K=50
        t.y = 0.0f;     // pairs with h1[51] == 0
        wreg[g * 13 + 12] = t;
      }
    }
#pragma unroll
    for (int p = 0; p < 52; ++p) wreg[p] = (p < 52) ? wreg[p] : wreg[p];
  }
  // uniform PIN (same shape every role -> single static allocation)
#pragma unroll
  for (int p = 0; p < 52; ++p) asm volatile("" : "+v"(wreg[p]));
#pragma unroll
  for (int g = 0; g < 4; ++g)
    asm volatile("" : "+v"(bias[g]), "+v"(wi1g[g]));
  asm volatile("" : "+v"(wlin_u));
  const float blin_s = blin[0];

  __syncthreads();

  // ======== main phase: 259 intervals x 4 steps, 1 barrier each ========
  for (int iv = 0; iv <= 258; ++iv) {
    if (wid < 2) {
      // L1 cell, seq = wid: 4 sequential steps, fully intra-wave.
      const int seq = wid;
      if (iv < 256) {
        const float* wsu = &lds_ws1[0][0][u][0];
        for (int s = 0; s < 4; ++s) {
          const int k = 4 * iv + s;
          float x = lds_x[seq][k];
          float acc[4];
#pragma unroll
          for (int g = 0; g < 4; ++g) acc[g] = fmaf(x, wi1g[g], bias[g]);
          cellDot1s(&lds_h1[(k - 1) & 7][seq][0], wsu, wreg, acc);
          float h = cell_update(acc, cst);
          if (act) lds_h1[k & 7][seq][u] = h;
        }
      }
    } else if (wid < 4) {
      // L2 cell, seq = wid-2: consumes piK one interval old.
      const int seq = wid - 2;
      if (iv >= 2 && iv <= 257) {
        const float* wsu = &lds_ws2[0][0][u][0];
        for (int s = 0; s < 4; ++s) {
          const int m = 4 * (iv - 2) + s;
          const int pm = m & 7;
          float acc[4];
#pragma unroll
          for (int g = 0; g < 4; ++g)
            acc[g] = bias[g] + lds_piK1[seq][pm][g][u] +
                     lds_piK2[seq][pm][g][u];
          cellDot1s(&lds_h2h[(m - 1) & (RING - 1)][seq][0], wsu, wreg, acc);
          float h = cell_update(acc, cst);
          if (act) lds_h2h[m & (RING - 1)][seq][u] = h;
        }
      }
    } else {
      // Wi2 quarter: consumes h1 one interval old; flush every 16.
      const int seq = (wid - 4) >> 1;
      const int kh = (wid - 4) & 1;
      const int koff = kh * 26;
      if (iv >= 1 && iv <= 256) {
        for (int s = 0; s < 4; ++s) {
          const int j = 4 * (iv - 1) + s;
          float acc[4];
          dotQ(&lds_h1[j & 7][seq][koff], wreg, acc);
          const int pm = j & 7;
          if (act) {
            float* dst =
                kh ? &lds_piK2[seq][pm][0][u] : &lds_piK1[seq][pm][0][u];
            dst[0 * PKR] = acc[0];
            dst[1 * PKR] = acc[1];
            dst[2 * PKR] = acc[2];
            dst[3 * PKR] = acc[3];
          }
        }
      }
      // FLUSH: kh==0 wave of EACH seq (wid4 -> seq0, wid6 -> seq1).
      if (kh == 0 && iv >= 18 && ((iv - 2) & 15) == 0) {
        const int c = 4 * (iv - 2) - 64;
        const int m = c + lane;
        const float* r = &lds_h2h[m & (RING - 1)][seq][0];
        const float4* r4 = reinterpret_cast<const float4*>(r);
        const float4* w4 = reinterpret_cast<const float4*>(lds_wlin);
        float o0 = 0.f, o1 = 0.f, o2 = 0.f, o3 = 0.f;
#pragma unroll
        for (int q = 0; q < 13; ++q) {  // wlin[51..]=0, r[51]=0
          float4 rv = r4[q];
          float4 wv = w4[q];
          o0 = fmaf(rv.x, wv.x, o0);
          o1 = fmaf(rv.y, wv.y, o1);
          o2 = fmaf(rv.z, wv.z, o2);
          o3 = fmaf(rv.w, wv.w, o3);
        }
        float o = (o0 + o1) + (o2 + o3) + blin_s;
        out[(s0 + seq) * TT + m] = o;
        if (m == TMAIN - 1) lds_fb[seq] = o;  // feedback seed
      }
    }
    __syncthreads();
  }

  // =============== feedback phase: 3 sub-phases, barriered ==============
  for (int t = TMAIN; t < TT; ++t) {
    float ph[4] = {0.f, 0.f, 0.f, 0.f};
    // --- A: L1 cells with feedback x; L2 waves pre-dot Wh2 @ h2(t-1) ---
    if (wid < 2) {
      const int seq = wid;
      float o = (t == TMAIN) ? lds_fb[seq] : lds_lin[seq];
      float acc[4];
#pragma unroll
      for (int g = 0; g < 4; ++g) acc[g] = fmaf(o, wi1g[g], bias[g]);
      cellDot1s(&lds_h1[(t - 1) & 7][seq][0], &lds_ws1[0][0][u][0], wreg,
                acc);
      float h = cell_update(acc, cst);
      if (act) lds_h1[t & 7][seq][u] = h;
    } else if (wid < 4) {
      cellDot1s(&lds_h2h[(t - 1) & (RING - 1)][wid - 2][0],
                &lds_ws2[0][0][u][0], wreg, ph);
    }
    __syncthreads();
    // --- B: Wi2 quarters from h1(t) ---
    if (wid >= 4) {
      const int seq = (wid - 4) >> 1;
      const int kh = (wid - 4) & 1;
      float acc[4];
      dotQ(&lds_h1[t & 7][seq][kh * 26], wreg, acc);
      const int pm = t & 7;
      if (act) {
        float* dst = kh ? &lds_piK2[seq][pm][0][u] : &lds_piK1[seq][pm][0][u];
        dst[0 * PKR] = acc[0];
        dst[1 * PKR] = acc[1];
        dst[2 * PKR] = acc[2];
        dst[3 * PKR] = acc[3];
      }
    }
    __syncthreads();
    // --- C: L2 cells + linear head butterfly (wid2 seq0, wid3 seq1) ---
    if (wid >= 2 && wid < 4) {
      const int seq = wid - 2;
      const int pm = t & 7;
      float acc[4];
#pragma unroll
      for (int g = 0; g < 4; ++g)
        acc[g] = bias[g] + lds_piK1[seq][pm][g][u] + lds_piK2[seq][pm][g][u] +
                 ph[g];
      float h = cell_update(acc, cst);
      float val = 0.0f;
      if (act) {
        lds_h2h[t & (RING - 1)][seq][u] = h;
        val = wlin_u * h;
      }
#pragma unroll
      for (int off = 32; off >= 1; off >>= 1) val += __shfl_xor(val, off);
      if (lane == 0) {
        float o = val + blin_s;
        lds_lin[seq] = o;
        lds_outbuf[seq][t - TMAIN] = o;
      }
    }
    __syncthreads();
  }

  // epilogue: flush the 64 future outputs (coalesced)
  if (wid == 4 || wid == 6) {
    const int seq = (wid - 4) >> 1;
    out[(s0 + seq) * TT + TMAIN + lane] = lds_outbuf[seq][lane];
  }
}

extern "C" void kernel_launch(void* const* d_in, const int* in_sizes, int n_in,
                              void* d_out, int out_size, void* d_ws,
                              size_t ws_size, hipStream_t stream) {
  const float* input = (const float*)d_in[0];
  const float* Wi1 = (const float*)d_in[1];
  const float* Wh1 = (const float*)d_in[2];
  const float* bi1 = (const float*)d_in[3];
  const float* bh1 = (const float*)d_in[4];
  const float* Wi2 = (const float*)d_in[5];
  const float* Wh2 = (const float*)d_in[6];
  const float* bi2 = (const float*)d_in[7];
  const float* bh2 = (const float*)d_in[8];
  const float* Wlin = (const float*)d_in[9];
  const float* blin = (const float*)d_in[10];
  float* out = (float*)d_out;

  const int B = in_sizes[0] / TMAIN;  // 512
  lstm2_persistent<<<B / 2, 512, 0, stream>>>(input, Wi1, Wh1, bi1, bh1, Wi2,
                                              Wh2, bi2, bh2, Wlin, blin, out);
}

// Round 18
// 1360.499 us; speedup vs baseline: 4.3855x; 1.4626x over previous
//
#include <hip/hip_runtime.h>
#include <math.h>

#define HID 51
#define TMAIN 1024
#define FUT 64
#define TT (TMAIN + FUT)
#define RING 128   // h2 history ring depth (pow2)
#define RPAD 68    // ring row stride in floats (16B-aligned, bank-skewed)

typedef float v2f __attribute__((ext_vector_type(2)));

__device__ __forceinline__ float fast_sigmoid(float x) {
  return 1.0f / (1.0f + __expf(-x));
}
__device__ __forceinline__ float fast_tanh(float x) {
  return 1.0f - 2.0f / (__expf(2.0f * x) + 1.0f);
}

// Dual-sequence packed full-K dot: acc{A,B}[g] += sum_k w[g][k]*h{A,B}[k].
// float4 LDS reads; a4[12] touches h[48..51] (element 51 loaded but unused).
__device__ __forceinline__ void dot2x(const float* hA, const float* hB,
                                      const v2f (&w2)[2][25],
                                      const float (&w50)[2],
                                      float (&aA)[2], float (&aB)[2]) {
  const float4* a4 = reinterpret_cast<const float4*>(hA);
  const float4* b4 = reinterpret_cast<const float4*>(hB);
  v2f sA0 = {0.f, 0.f}, sA1 = {0.f, 0.f};
  v2f sB0 = {0.f, 0.f}, sB1 = {0.f, 0.f};
#pragma unroll
  for (int q = 0; q < 12; ++q) {
    float4 av = a4[q];
    float4 bv = b4[q];
    v2f alo = {av.x, av.y}, ahi = {av.z, av.w};
    v2f blo = {bv.x, bv.y}, bhi = {bv.z, bv.w};
    sA0 = __builtin_elementwise_fma(alo, w2[0][2 * q + 0], sA0);
    sB0 = __builtin_elementwise_fma(blo, w2[0][2 * q + 0], sB0);
    sA1 = __builtin_elementwise_fma(alo, w2[1][2 * q + 0], sA1);
    sB1 = __builtin_elementwise_fma(blo, w2[1][2 * q + 0], sB1);
    sA0 = __builtin_elementwise_fma(ahi, w2[0][2 * q + 1], sA0);
    sB0 = __builtin_elementwise_fma(bhi, w2[0][2 * q + 1], sB0);
    sA1 = __builtin_elementwise_fma(ahi, w2[1][2 * q + 1], sA1);
    sB1 = __builtin_elementwise_fma(bhi, w2[1][2 * q + 1], sB1);
  }
  float4 at = a4[12];
  float4 bt = b4[12];
  v2f alo = {at.x, at.y}, blo = {bt.x, bt.y};
  sA0 = __builtin_elementwise_fma(alo, w2[0][24], sA0);
  sB0 = __builtin_elementwise_fma(blo, w2[0][24], sB0);
  sA1 = __builtin_elementwise_fma(alo, w2[1][24], sA1);
  sB1 = __builtin_elementwise_fma(blo, w2[1][24], sB1);
  aA[0] = fmaf(at.z, w50[0], aA[0] + sA0.x + sA0.y);
  aB[0] = fmaf(bt.z, w50[0], aB[0] + sB0.x + sB0.y);
  aA[1] = fmaf(at.z, w50[1], aA[1] + sA1.x + sA1.y);
  aB[1] = fmaf(bt.z, w50[1], aB[1] + sB1.x + sB1.y);
}

// Half-K dual-seq dot: 13 float2 pairs starting at a pre-offset pointer.
// K2 waves' pair 12 multiplies {h[50],h[51]} by {w50,0}; h1[51] is kept 0.
__device__ __forceinline__ void dotH(const float* hA, const float* hB,
                                     const v2f (&w)[2][13],
                                     float (&aA)[2], float (&aB)[2]) {
  const float2* a2 = reinterpret_cast<const float2*>(hA);
  const float2* b2 = reinterpret_cast<const float2*>(hB);
  v2f sA0 = {0.f, 0.f}, sA1 = {0.f, 0.f};
  v2f sB0 = {0.f, 0.f}, sB1 = {0.f, 0.f};
#pragma unroll
  for (int p = 0; p < 13; ++p) {
    float2 av = a2[p], bv = b2[p];
    v2f a = {av.x, av.y}, b = {bv.x, bv.y};
    sA0 = __builtin_elementwise_fma(a, w[0][p], sA0);
    sB0 = __builtin_elementwise_fma(b, w[0][p], sB0);
    sA1 = __builtin_elementwise_fma(a, w[1][p], sA1);
    sB1 = __builtin_elementwise_fma(b, w[1][p], sB1);
  }
  aA[0] = sA0.x + sA0.y;
  aB[0] = sB0.x + sB0.y;
  aA[1] = sA1.x + sA1.y;
  aB[1] = sB1.x + sB1.y;
}

// One block = TWO sequences, 8 waves (best-known configuration, R9-bench):
//   wid0,1: L1 cell, units [0,26)/[26,51)
//   wid2,3: Wh2 cell (L2), units [0,26)/[26,51)   [carry c2; feedback lin]
//   wid4,5: Wi2 K[26,51) partial -> piK2           [+ main-phase out flush]
//   wid6,7: Wi2 K[0,26)  partial -> piK1
// Pipeline skew (1 barrier/interval): h1(k) | piK(k-1) | h2(k-2).
// Linear head is OUT of the loop: h2 history in a 128-ring; every 64
// intervals waves 4,5 compute+store 64 outputs each (plain 51-FMA dots).
// Feedback phase (out->x serial) runs a 3-sub-phase barriered schedule.
// Session summary (R10-R17 all tied or regressed vs this):
//  - piS float4 gather: null (+29M bank conflicts ate the gain)
//  - LDS flag sync: +19% (per-hop spin > s_barrier)
//  - wave-local cells (204 w/lane): spills regardless of pin ("v"/"a");
//    empirical 128-arch-VGPR allocator wall, 4 data points
//  - 4-step barrier intervals + streamed gates: +43-50% (serial chain
//    concentration beats barrier savings)
// => latency floor ~3.2k cy/step for this dependency graph at 1 block/CU.
__global__ __launch_bounds__(512, 2)
void lstm2_persistent(const float* __restrict__ input,
                      const float* __restrict__ Wi1,
                      const float* __restrict__ Wh1,
                      const float* __restrict__ bi1,
                      const float* __restrict__ bh1,
                      const float* __restrict__ Wi2,
                      const float* __restrict__ Wh2,
                      const float* __restrict__ bi2,
                      const float* __restrict__ bh2,
                      const float* __restrict__ Wlin,
                      const float* __restrict__ blin,
                      float* __restrict__ out) {
  __shared__ __align__(16) float lds_x[2][TMAIN];          // [seq][t]
  __shared__ __align__(16) float lds_h1[2][2][64];         // [seq][parity][u]
  __shared__ __align__(16) float lds_piK1[2][2][4][64];    // [par][seq][g][u]
  __shared__ __align__(16) float lds_piK2[2][2][4][64];    // [par][seq][g][u]
  __shared__ __align__(16) float lds_h2h[2][RING][RPAD];   // h2 history ring
  __shared__ __align__(16) float lds_wlin[64];
  __shared__ __align__(16) float lds_outbuf[2][64];        // feedback outputs
  __shared__ float lds_lin[2][2][2];                       // [par][seq][cellw]
  __shared__ float lds_fb[2];                              // out(1023) seed

  const int tid = threadIdx.x;
  const int s0 = blockIdx.x * 2;  // sequence pair
  const int wid = tid >> 6;       // 0..7
  const int lane = tid & 63;
  const int half = lane >> 5;   // 0: gates {i,f}, 1: gates {g,o}
  const int l5 = lane & 31;
  const int base = (wid & 1) * 26;
  const int nu = (wid & 1) ? 25 : 26;
  const bool act = l5 < nu;
  const int u = base + (act ? l5 : 0);  // clamped unit index
  const int g0 = half * 2;
  const int koff = (wid >= 6) ? 0 : 26;  // Wi2 K-half offset

  // Stage inputs; zero h1 buffers (incl. elem 51..63 -> dotH pair-12 safe)
  // and ring slot RING-1 (h2(-1) = 0); stage wlin.
  for (int i = tid; i < TMAIN; i += 512) {
    lds_x[0][i] = input[s0 * TMAIN + i];
    lds_x[1][i] = input[(s0 + 1) * TMAIN + i];
  }
  if (tid < 64) {
    lds_h1[0][0][tid] = 0.0f;
    lds_h1[0][1][tid] = 0.0f;
    lds_h1[1][0][tid] = 0.0f;
    lds_h1[1][1][tid] = 0.0f;
    lds_wlin[tid] = (tid < HID) ? Wlin[tid] : 0.0f;
  }
  if (tid < 128) lds_h2h[tid >> 6][RING - 1][tid & 63] = 0.0f;

  // ---- weights ----
  v2f w2f[2][25];  // full rows (L1 / Wh2 cell waves)
  float w50f[2] = {0.f, 0.f};
  v2f w2h[2][13];  // half rows (Wi2 waves)
  float bias[2] = {0.f, 0.f};
  float wi1g[2] = {0.f, 0.f};
  float wlin_u = 0.0f;
  float cA = 0.0f, cB = 0.0f;  // cell states (L1 in wid01, L2 in wid23)

  if (wid < 4) {
    const float* Wsel = (wid < 2) ? Wh1 : Wh2;
#pragma unroll
    for (int g = 0; g < 2; ++g) {
      const float* row = Wsel + ((g0 + g) * HID + u) * HID;
#pragma unroll
      for (int p = 0; p < 25; ++p) {
        v2f t;
        t.x = row[2 * p + 0];
        t.y = row[2 * p + 1];
        w2f[g][p] = t;
      }
      w50f[g] = row[50];
    }
    if (wid < 2) {
#pragma unroll
      for (int g = 0; g < 2; ++g) {
        bias[g] = bi1[(g0 + g) * HID + u] + bh1[(g0 + g) * HID + u];
        wi1g[g] = Wi1[(g0 + g) * HID + u];
      }
    } else {
      wlin_u = Wlin[u];  // feedback-phase butterfly weight
    }
#pragma unroll
    for (int g = 0; g < 2; ++g) {
#pragma unroll
      for (int p = 0; p < 25; ++p) asm volatile("" : "+v"(w2f[g][p]));
      asm volatile("" : "+v"(w50f[g]), "+v"(bias[g]), "+v"(wi1g[g]));
    }
    asm volatile("" : "+v"(wlin_u));
  } else {
#pragma unroll
    for (int g = 0; g < 2; ++g) {
      const float* row = Wi2 + ((g0 + g) * HID + u) * HID + koff;
      if (koff == 0) {
#pragma unroll
        for (int p = 0; p < 13; ++p) {
          v2f t;
          t.x = row[2 * p + 0];
          t.y = row[2 * p + 1];
          w2h[g][p] = t;
        }
      } else {
#pragma unroll
        for (int p = 0; p < 12; ++p) {
          v2f t;
          t.x = row[2 * p + 0];
          t.y = row[2 * p + 1];
          w2h[g][p] = t;
        }
        v2f t;
        t.x = row[24];  // K=50
        t.y = 0.0f;     // pairs with h1[51] == 0
        w2h[g][12] = t;
      }
    }
    if (koff == 26) {  // K2 waves carry bias2 (folded into their piK writes)
#pragma unroll
      for (int g = 0; g < 2; ++g)
        bias[g] = bi2[(g0 + g) * HID + u] + bh2[(g0 + g) * HID + u];
    }
#pragma unroll
    for (int g = 0; g < 2; ++g) {
#pragma unroll
      for (int p = 0; p < 13; ++p) asm volatile("" : "+v"(w2h[g][p]));
      asm volatile("" : "+v"(bias[g]));
    }
  }
  const float blin_s = blin[0];

  __syncthreads();

  // =============== main-phase pipeline: one barrier per interval ========
  for (int k = 0; k <= TMAIN + 2; ++k) {
    if (wid < 2) {
      if (k < TMAIN) {
        // h1(k) = cell1(x(k), h1(k-1));  h1(m) lives in buffer (m+1)&1
        float xA = lds_x[0][k], xB = lds_x[1][k];
        float aA[2], aB[2];
#pragma unroll
        for (int g = 0; g < 2; ++g) {
          aA[g] = fmaf(xA, wi1g[g], bias[g]);
          aB[g] = fmaf(xB, wi1g[g], bias[g]);
        }
        dot2x(lds_h1[0][k & 1], lds_h1[1][k & 1], w2f, w50f, aA, aB);
        float pA0 = __shfl_xor(aA[0], 32), pA1 = __shfl_xor(aA[1], 32);
        float pB0 = __shfl_xor(aB[0], 32), pB1 = __shfl_xor(aB[1], 32);
        float giA = half ? pA0 : aA[0], gfA = half ? pA1 : aA[1];
        float ggA = half ? aA[0] : pA0, goA = half ? aA[1] : pA1;
        float giB = half ? pB0 : aB[0], gfB = half ? pB1 : aB[1];
        float ggB = half ? aB[0] : pB0, goB = half ? aB[1] : pB1;
        cA = fast_sigmoid(gfA) * cA + fast_sigmoid(giA) * fast_tanh(ggA);
        cB = fast_sigmoid(gfB) * cB + fast_sigmoid(giB) * fast_tanh(ggB);
        float hA = fast_sigmoid(goA) * fast_tanh(cA);
        float hB = fast_sigmoid(goB) * fast_tanh(cB);
        if (act && half == 0) {
          lds_h1[0][(k + 1) & 1][u] = hA;
          lds_h1[1][(k + 1) & 1][u] = hB;
        }
      }
    } else if (wid < 4) {
      if (k >= 2 && k <= TMAIN + 1) {
        // h2(m2) = cell2(bias + piK1(m2)+piK2(m2) + Wh2 @ h2(m2-1))
        const int m2 = k - 2;
        const int pm = m2 & 1;
        float aA[2], aB[2];
        aA[0] = lds_piK1[pm][0][g0 + 0][u] + lds_piK2[pm][0][g0 + 0][u];
        aA[1] = lds_piK1[pm][0][g0 + 1][u] + lds_piK2[pm][0][g0 + 1][u];
        aB[0] = lds_piK1[pm][1][g0 + 0][u] + lds_piK2[pm][1][g0 + 0][u];
        aB[1] = lds_piK1[pm][1][g0 + 1][u] + lds_piK2[pm][1][g0 + 1][u];
        dot2x(&lds_h2h[0][(m2 - 1) & (RING - 1)][0],
              &lds_h2h[1][(m2 - 1) & (RING - 1)][0], w2f, w50f, aA, aB);
        float pA0 = __shfl_xor(aA[0], 32), pA1 = __shfl_xor(aA[1], 32);
        float pB0 = __shfl_xor(aB[0], 32), pB1 = __shfl_xor(aB[1], 32);
        float giA = half ? pA0 : aA[0], gfA = half ? pA1 : aA[1];
        float ggA = half ? aA[0] : pA0, goA = half ? aA[1] : pA1;
        float giB = half ? pB0 : aB[0], gfB = half ? pB1 : aB[1];
        float ggB = half ? aB[0] : pB0, goB = half ? aB[1] : pB1;
        cA = fast_sigmoid(gfA) * cA + fast_sigmoid(giA) * fast_tanh(ggA);
        cB = fast_sigmoid(gfB) * cB + fast_sigmoid(giB) * fast_tanh(ggB);
        float hA = fast_sigmoid(goA) * fast_tanh(cA);
        float hB = fast_sigmoid(goB) * fast_tanh(cB);
        if (act && half == 0) {
          lds_h2h[0][m2 & (RING - 1)][u] = hA;
          lds_h2h[1][m2 & (RING - 1)][u] = hB;
        }
      }
    } else {
      if (k >= 1 && k <= TMAIN) {
        // piK(k-1) partial: Wi2[:, koff:koff+26] @ h1(k-1)[koff:...]
        // (bias2 folded into the K2 waves' partials)
        float aA[2], aB[2];
        dotH(&lds_h1[0][k & 1][koff], &lds_h1[1][k & 1][koff], w2h, aA, aB);
        const int pm = (k - 1) & 1;
        if (act) {
          if (koff == 26) {
            aA[0] += bias[0];
            aA[1] += bias[1];
            aB[0] += bias[0];
            aB[1] += bias[1];
            lds_piK2[pm][0][g0 + 0][u] = aA[0];
            lds_piK2[pm][0][g0 + 1][u] = aA[1];
            lds_piK2[pm][1][g0 + 0][u] = aB[0];
            lds_piK2[pm][1][g0 + 1][u] = aB[1];
          } else {
            lds_piK1[pm][0][g0 + 0][u] = aA[0];
            lds_piK1[pm][0][g0 + 1][u] = aA[1];
            lds_piK1[pm][1][g0 + 0][u] = aB[0];
            lds_piK1[pm][1][g0 + 1][u] = aB[1];
          }
        }
      }
      // Deferred linear head: every 64 intervals, waves 4,5 emit 64 outs
      // each (chunk c=k-66; h2(c+63) landed at interval c+65; writer this
      // interval touches slot (c+64)&127 -- disjoint from read slots).
      if (wid < 6 && k >= 66 && ((k - 66) & 63) == 0) {
        const int c = k - 66;
        const int seq = wid - 4;
        const int m = c + lane;
        const float* r = &lds_h2h[seq][m & (RING - 1)][0];
        const float4* r4 = reinterpret_cast<const float4*>(r);
        const float4* w4 = reinterpret_cast<const float4*>(lds_wlin);
        float o0 = 0.f, o1 = 0.f, o2 = 0.f, o3 = 0.f;
#pragma unroll
        for (int q = 0; q < 12; ++q) {
          float4 rv = r4[q];
          float4 wv = w4[q];
          o0 = fmaf(rv.x, wv.x, o0);
          o1 = fmaf(rv.y, wv.y, o1);
          o2 = fmaf(rv.z, wv.z, o2);
          o3 = fmaf(rv.w, wv.w, o3);
        }
        o0 = fmaf(r[48], lds_wlin[48], o0);
        o1 = fmaf(r[49], lds_wlin[49], o1);
        o2 = fmaf(r[50], lds_wlin[50], o2);
        float o = (o0 + o1) + (o2 + o3) + blin_s;
        out[(s0 + seq) * TT + m] = o;
        if (m == TMAIN - 1) lds_fb[seq] = o;  // feedback seed
      }
    }
    __syncthreads();
  }

  // =============== feedback phase: 3 sub-phases, barriered ==============
  for (int t = TMAIN; t < TT; ++t) {
    float phA[2] = {0.f, 0.f}, phB[2] = {0.f, 0.f};
    // --- A: L1 cell with feedback x; cell waves pre-dot Wh2 @ h2(t-1) ---
    if (wid < 2) {
      float oA, oB;
      if (t == TMAIN) {
        oA = lds_fb[0];
        oB = lds_fb[1];
      } else {
        oA = lds_lin[(t - 1) & 1][0][0] + lds_lin[(t - 1) & 1][0][1] + blin_s;
        oB = lds_lin[(t - 1) & 1][1][0] + lds_lin[(t - 1) & 1][1][1] + blin_s;
        if (lane == 0) {  // buffer future outputs; flushed in epilogue
          if (wid == 0) lds_outbuf[0][t - 1 - TMAIN] = oA;
          else          lds_outbuf[1][t - 1 - TMAIN] = oB;
        }
      }
      float aA[2], aB[2];
#pragma unroll
      for (int g = 0; g < 2; ++g) {
        aA[g] = fmaf(oA, wi1g[g], bias[g]);
        aB[g] = fmaf(oB, wi1g[g], bias[g]);
      }
      dot2x(lds_h1[0][t & 1], lds_h1[1][t & 1], w2f, w50f, aA, aB);
      float pA0 = __shfl_xor(aA[0], 32), pA1 = __shfl_xor(aA[1], 32);
      float pB0 = __shfl_xor(aB[0], 32), pB1 = __shfl_xor(aB[1], 32);
      float giA = half ? pA0 : aA[0], gfA = half ? pA1 : aA[1];
      float ggA = half ? aA[0] : pA0, goA = half ? aA[1] : pA1;
      float giB = half ? pB0 : aB[0], gfB = half ? pB1 : aB[1];
      float ggB = half ? aB[0] : pB0, goB = half ? aB[1] : pB1;
      cA = fast_sigmoid(gfA) * cA + fast_sigmoid(giA) * fast_tanh(ggA);
      cB = fast_sigmoid(gfB) * cB + fast_sigmoid(giB) * fast_tanh(ggB);
      float hA = fast_sigmoid(goA) * fast_tanh(cA);
      float hB = fast_sigmoid(goB) * fast_tanh(cB);
      if (act && half == 0) {
        lds_h1[0][(t + 1) & 1][u] = hA;
        lds_h1[1][(t + 1) & 1][u] = hB;
      }
    } else if (wid < 4) {
      dot2x(&lds_h2h[0][(t - 1) & (RING - 1)][0],
            &lds_h2h[1][(t - 1) & (RING - 1)][0], w2f, w50f, phA, phB);
    }
    __syncthreads();
    // --- B: piK halves from h1(t) ---
    if (wid >= 4) {
      float aA[2], aB[2];
      dotH(&lds_h1[0][(t + 1) & 1][koff], &lds_h1[1][(t + 1) & 1][koff], w2h,
           aA, aB);
      const int pm = t & 1;
      if (act) {
        if (koff == 26) {
          aA[0] += bias[0];
          aA[1] += bias[1];
          aB[0] += bias[0];
          aB[1] += bias[1];
          lds_piK2[pm][0][g0 + 0][u] = aA[0];
          lds_piK2[pm][0][g0 + 1][u] = aA[1];
          lds_piK2[pm][1][g0 + 0][u] = aB[0];
          lds_piK2[pm][1][g0 + 1][u] = aB[1];
        } else {
          lds_piK1[pm][0][g0 + 0][u] = aA[0];
          lds_piK1[pm][0][g0 + 1][u] = aA[1];
          lds_piK1[pm][1][g0 + 0][u] = aB[0];
          lds_piK1[pm][1][g0 + 1][u] = aB[1];
        }
      }
    }
    __syncthreads();
    // --- C: L2 cell + linear head (butterfly on cell waves here) ---
    if (wid >= 2 && wid < 4) {
      const int pm = t & 1;
      float aA[2], aB[2];
      aA[0] = lds_piK1[pm][0][g0 + 0][u] + lds_piK2[pm][0][g0 + 0][u] + phA[0];
      aA[1] = lds_piK1[pm][0][g0 + 1][u] + lds_piK2[pm][0][g0 + 1][u] + phA[1];
      aB[0] = lds_piK1[pm][1][g0 + 0][u] + lds_piK2[pm][1][g0 + 0][u] + phB[0];
      aB[1] = lds_piK1[pm][1][g0 + 1][u] + lds_piK2[pm][1][g0 + 1][u] + phB[1];
      float pA0 = __shfl_xor(aA[0], 32), pA1 = __shfl_xor(aA[1], 32);
      float pB0 = __shfl_xor(aB[0], 32), pB1 = __shfl_xor(aB[1], 32);
      float giA = half ? pA0 : aA[0], gfA = half ? pA1 : aA[1];
      float ggA = half ? aA[0] : pA0, goA = half ? aA[1] : pA1;
      float giB = half ? pB0 : aB[0], gfB = half ? pB1 : aB[1];
      float ggB = half ? aB[0] : pB0, goB = half ? aB[1] : pB1;
      cA = fast_sigmoid(gfA) * cA + fast_sigmoid(giA) * fast_tanh(ggA);
      cB = fast_sigmoid(gfB) * cB + fast_sigmoid(giB) * fast_tanh(ggB);
      float hA = fast_sigmoid(goA) * fast_tanh(cA);
      float hB = fast_sigmoid(goB) * fast_tanh(cB);
      float val = 0.0f;
      if (act) {
        if (half == 0) {
          lds_h2h[0][t & (RING - 1)][u] = hA;
          val = wlin_u * hA;
        } else {
          lds_h2h[1][t & (RING - 1)][u] = hB;
          val = wlin_u * hB;
        }
      }
#pragma unroll
      for (int off = 16; off >= 1; off >>= 1) val += __shfl_xor(val, off);
      if (lane == 0) lds_lin[t & 1][0][wid - 2] = val;
      if (lane == 32) lds_lin[t & 1][1][wid - 2] = val;
    }
    __syncthreads();
  }

  // epilogue: buffer out(TT-1), then flush the 64 future outputs
  if (wid < 2 && lane == 0) {
    float o = lds_lin[(TT - 1) & 1][wid][0] + lds_lin[(TT - 1) & 1][wid][1] +
              blin_s;
    lds_outbuf[wid][63] = o;
  }
  __syncthreads();
  if (wid == 4 || wid == 5) {
    const int seq = wid - 4;
    out[(s0 + seq) * TT + TMAIN + lane] = lds_outbuf[seq][lane];
  }
}

extern "C" void kernel_launch(void* const* d_in, const int* in_sizes, int n_in,
                              void* d_out, int out_size, void* d_ws,
                              size_t ws_size, hipStream_t stream) {
  const float* input = (const float*)d_in[0];
  const float* Wi1 = (const float*)d_in[1];
  const float* Wh1 = (const float*)d_in[2];
  const float* bi1 = (const float*)d_in[3];
  const float* bh1 = (const float*)d_in[4];
  const float* Wi2 = (const float*)d_in[5];
  const float* Wh2 = (const float*)d_in[6];
  const float* bi2 = (const float*)d_in[7];
  const float* bh2 = (const float*)d_in[8];
  const float* Wlin = (const float*)d_in[9];
  const float* blin = (const float*)d_in[10];
  float* out = (float*)d_out;

  const int B = in_sizes[0] / TMAIN;  // 512
  lstm2_persistent<<<B / 2, 512, 0, stream>>>(input, Wi1, Wh1, bi1, bh1, Wi2,
                                              Wh2, bi2, bh2, Wlin, blin, out);
}